// Round 1
// baseline (264.024 us; speedup 1.0000x reference)
//
#include <hip/hip_runtime.h>
#include <cstdint>

// Multi-kernel train (9 dispatches + 8MB memset), R1-validated math,
// fused stages:
//  K1 memset(WadjT,Adn)
//  K2 mm64 (8192 blks) + edge scatter (256 blks)
//  K3 dinv
//  K4 gcn + s1 fused (ballot compaction, block per node)
//  K5 AS1 (1024 blks) + x1 (128 blks)
//  K6 pool1 (16 blks x 1024 thr)
//  K7 conv2 (128 blks)
//  K8 s2 (1024 blks x 64)
//  K9 x3 (128) + pool2 (16)
//  K10 conv3 (128) + agg (512) + losses (1)

#define WS_WADJT 0
#define WS_ADN   1048576
#define WS_XW    2097152
#define WS_H     4194304
#define WS_DINV  6291456
#define WS_S1    6295552
#define WS_TMP   6557696
#define WS_DFLAT 6819840
#define WS_ADJ1  6823936
#define WS_X1    6889472
#define WS_X2    7413760
#define WS_X3    7938048
#define WS_S2    8200192
#define WS_ADJ2  8232960
#define WS_SCAL  8249344

__device__ __forceinline__ void fma4(float4& a, float s, const float4& v) {
  a.x += s * v.x; a.y += s * v.y; a.z += s * v.z; a.w += s * v.w;
}

// 256-thread (4-wave) block reduction, red[4]
__device__ __forceinline__ float blockRedSum4(float v, float* red) {
  #pragma unroll
  for (int m = 32; m; m >>= 1) v += __shfl_xor(v, m);
  __syncthreads();
  if ((threadIdx.x & 63) == 0) red[threadIdx.x >> 6] = v;
  __syncthreads();
  return red[0] + red[1] + red[2] + red[3];
}

// 1024-thread (16-wave) block reduction, red[16]
__device__ __forceinline__ float blockRedSum16(float v, float* red) {
  #pragma unroll
  for (int m = 32; m; m >>= 1) v += __shfl_xor(v, m);
  __syncthreads();
  if ((threadIdx.x & 63) == 0) red[threadIdx.x >> 6] = v;
  __syncthreads();
  float s = 0.f;
  #pragma unroll
  for (int i = 0; i < 16; ++i) s += red[i];
  __syncthreads();
  return s;
}

// ---------------- K2: xw = pos @ W1 (blocks 0..8191) + scatter (8192..8447)
__global__ __launch_bounds__(256) void k_p0(const float* __restrict__ pos,
                                            const float* __restrict__ W1,
                                            const int* __restrict__ ei,
                                            const float* __restrict__ ea,
                                            float* __restrict__ ws) {
  int tid = threadIdx.x, blk = blockIdx.x;
  __shared__ float sB[4096];
  if (blk < 8192) {
    for (int i = tid; i < 4096; i += 256) sB[i] = W1[i];
    __syncthreads();
    int row = blk * 4 + (tid >> 6), col = tid & 63;
    const float* a = pos + (size_t)row * 64;
    float acc = 0.f;
    #pragma unroll 8
    for (int k = 0; k < 64; ++k) acc += a[k] * sB[k * 64 + col];
    ws[WS_XW + (size_t)row * 64 + col] = acc;
  } else {
    int e = (blk - 8192) * 256 + tid;
    int s = ei[e], d = ei[65536 + e];
    int g = s >> 8, r = s & 255, c = d & 255;
    atomicAdd(&ws[WS_WADJT + (((g << 8) + c) << 8) + r], ea[e]);
    atomicAdd(&ws[WS_ADN + (((g << 8) + r) << 8) + c], 1.0f);
  }
}

// ---------------- K3: dinv = rsqrt(1 + rowsum(WadjT))
__global__ __launch_bounds__(256) void k_dinv(float* __restrict__ ws) {
  int n = blockIdx.x * 4 + (threadIdx.x >> 6);
  int lane = threadIdx.x & 63;
  const float* row = ws + WS_WADJT + (size_t)n * 256;
  float s = row[lane] + row[64 + lane] + row[128 + lane] + row[192 + lane];
  #pragma unroll
  for (int m = 32; m; m >>= 1) s += __shfl_xor(s, m);
  if (lane == 0) ws[WS_DINV + n] = rsqrtf(s + 1.0f);
}

// ---------------- K4: GCN aggregate + relu -> h, then s1 softmax (fused)
__global__ __launch_bounds__(256) void k_gcn_s1(float* __restrict__ ws,
                                                const float* __restrict__ b1,
                                                const float* __restrict__ p1W,
                                                const float* __restrict__ p1b) {
  __shared__ float pL[256];
  __shared__ int iL[256];
  __shared__ int wcnt[4];
  __shared__ float red4[256];
  __shared__ float xm[64];
  int n = blockIdx.x;
  int g = n >> 8, cc = n & 255;
  int tid = threadIdx.x;
  int w = tid >> 6, lane = tid & 63;
  const float* dinv = ws + WS_DINV;
  float dn = dinv[n];
  float pv = ws[WS_WADJT + (size_t)n * 256 + tid] * dinv[(g << 8) + tid] * dn;
  if (tid == cc) pv += dn * dn;
  bool act = (pv != 0.f);
  unsigned long long mask = __ballot(act);
  int wpos = (int)__popcll(mask & ((1ull << lane) - 1ull));
  if (lane == 0) wcnt[w] = (int)__popcll(mask);
  __syncthreads();
  int base = 0;
  #pragma unroll
  for (int i = 0; i < 4; ++i) base += (i < w) ? wcnt[i] : 0;
  int na = wcnt[0] + wcnt[1] + wcnt[2] + wcnt[3];
  if (act) { iL[base + wpos] = tid; pL[base + wpos] = pv; }
  __syncthreads();
  const float* xg = ws + WS_XW + (size_t)g * 131072;
  float acc0 = 0.f, acc1 = 0.f;
  for (int i = 0; i < na; ++i) {
    int r = iL[i];
    float p = pL[i];
    acc0 += p * xg[(size_t)r * 512 + tid];
    acc1 += p * xg[(size_t)r * 512 + 256 + tid];
  }
  float bb = b1[tid & 63];
  acc0 = fmaxf(acc0 + bb, 0.f);
  acc1 = fmaxf(acc1 + bb, 0.f);
  float* hp = ws + WS_H + (size_t)n * 512;
  hp[tid] = acc0;
  hp[256 + tid] = acc1;
  // mean over t: element (t=w,f) + (t=w+4,f)
  red4[w * 64 + (tid & 63)] = acc0 + acc1;
  __syncthreads();
  if (tid < 64) {
    xm[tid] = 0.125f * (red4[tid] + red4[64 + tid] + red4[128 + tid] + red4[192 + tid]);
    float a = p1b[tid];
    #pragma unroll 4
    for (int k = 0; k < 64; ++k) a += xm[k] * p1W[k * 64 + tid];
    float v = tanhf(a);
    float mx = v;
    #pragma unroll
    for (int m = 32; m; m >>= 1) mx = fmaxf(mx, __shfl_xor(mx, m));
    float e = __expf(v - mx);
    float se = e;
    #pragma unroll
    for (int m = 32; m; m >>= 1) se += __shfl_xor(se, m);
    ws[WS_S1 + (size_t)n * 64 + tid] = e / se;
  }
}

// ---------------- K5: AS1 (blocks 0..1023, wave/node) + x1 (blocks 1024..1151)
__global__ __launch_bounds__(256) void k_as1_x1(float* __restrict__ ws) {
  __shared__ float smem[4096];
  int tid = threadIdx.x, blk = blockIdx.x;
  if (blk < 1024) {
    int* iL = (int*)smem;        // 1024 ints
    float* aL = smem + 1024;     // 1024 floats
    int w = tid >> 6, lane = tid & 63;
    int n = blk * 4 + w, g = n >> 8;
    float4 av = *(const float4*)(ws + WS_ADN + (size_t)n * 256 + lane * 4);
    float rs = av.x + av.y + av.z + av.w;
    #pragma unroll
    for (int m = 32; m; m >>= 1) rs += __shfl_xor(rs, m);
    if (lane == 0) ws[WS_DFLAT + n] = rs;
    float avv[4] = {av.x, av.y, av.z, av.w};
    unsigned long long below = (1ull << lane) - 1ull;
    int base = 0;
    #pragma unroll
    for (int q = 0; q < 4; ++q) {
      bool act = (avv[q] != 0.f);
      unsigned long long mask = __ballot(act);
      if (act) {
        int pos = base + (int)__popcll(mask & below);
        iL[w * 256 + pos] = lane * 4 + q;
        aL[w * 256 + pos] = avv[q];
      }
      base += (int)__popcll(mask);
    }
    int na = base;
    float acc = 0.f;
    const float* S1g = ws + WS_S1 + ((size_t)g << 8) * 64;
    for (int i = 0; i < na; ++i) {
      int m = iL[w * 256 + i];
      float a = aL[w * 256 + i];
      acc += a * S1g[(size_t)m * 64 + lane];
    }
    ws[WS_TMP + (size_t)n * 64 + lane] = acc;
  } else {
    // x1[b,t,k,h] = sum_n S1[b,n,k] h[b,n,t,h]
    int bt = blk - 1024;
    int b = bt >> 3, t = bt & 7;
    int hc = tid & 63, kb = (tid >> 6) * 16;
    float* sS = smem;          // 2048
    float* sX = smem + 2048;   // 2048
    float acc[16];
    #pragma unroll
    for (int q = 0; q < 16; ++q) acc[q] = 0.f;
    for (int n0 = 0; n0 < 256; n0 += 32) {
      __syncthreads();
      for (int idx = tid; idx < 2048; idx += 256) {
        int i = idx >> 6, c = idx & 63;
        sS[idx] = ws[WS_S1 + ((size_t)((b << 8) + n0 + i)) * 64 + c];
        sX[idx] = ws[WS_H + ((size_t)((b << 8) + n0 + i)) * 512 + t * 64 + c];
      }
      __syncthreads();
      for (int i = 0; i < 32; ++i) {
        float xv = sX[i * 64 + hc];
        #pragma unroll
        for (int q = 0; q < 16; ++q) acc[q] += sS[i * 64 + kb + q] * xv;
      }
    }
    #pragma unroll
    for (int q = 0; q < 16; ++q)
      ws[WS_X1 + ((size_t)bt * 64 + kb + q) * 64 + hc] = acc[q];
  }
}

// ---------------- K6: pool1 (16 blocks x 1024 threads)
__global__ __launch_bounds__(1024) void k_pool1(float* __restrict__ ws) {
  __shared__ float S1c[2048];
  __shared__ float Tc[2048];
  __shared__ float prs[1088];   // 64*17
  __shared__ float diagL[64];
  __shared__ float dd[64];
  __shared__ float red[16];
  int b = blockIdx.x, tid = threadIdx.x;
  int k = tid >> 4, j0 = (tid & 15) * 4;
  const float* Sb = ws + WS_S1 + (size_t)b * 16384;
  const float* Tb = ws + WS_TMP + (size_t)b * 16384;
  float accA[4] = {0, 0, 0, 0}, accS[4] = {0, 0, 0, 0};
  for (int n0 = 0; n0 < 256; n0 += 32) {
    __syncthreads();
    S1c[tid] = Sb[n0 * 64 + tid];
    S1c[tid + 1024] = Sb[n0 * 64 + 1024 + tid];
    Tc[tid] = Tb[n0 * 64 + tid];
    Tc[tid + 1024] = Tb[n0 * 64 + 1024 + tid];
    __syncthreads();
    for (int i = 0; i < 32; ++i) {
      float sk = S1c[i * 64 + k];
      float4 tv = *(const float4*)(Tc + i * 64 + j0);
      float4 sv = *(const float4*)(S1c + i * 64 + j0);
      fma4(*(float4*)accA, sk, tv);
      fma4(*(float4*)accS, sk, sv);
    }
  }
  float num = 0.f, fro2 = 0.f, rsp = 0.f;
  #pragma unroll
  for (int q = 0; q < 4; ++q) { rsp += accA[q]; fro2 += accS[q] * accS[q]; }
  if (k >= j0 && k < j0 + 4) { num = accA[k - j0]; diagL[k] = accA[k - j0]; }
  prs[k * 17 + (tid & 15)] = rsp;
  __syncthreads();
  if (tid < 64) {
    float rs = 0.f;
    #pragma unroll
    for (int i = 0; i < 16; ++i) rs += prs[tid * 17 + i];
    dd[tid] = sqrtf(fmaxf(rs - diagL[tid], 0.f)) + 1e-15f;
  }
  float denp = 0.f;
  if (tid < 256) {
    const float* s = Sb + tid * 64;
    float q = 0.f;
    for (int kk = 0; kk < 64; kk += 4) {
      float4 v = *(const float4*)(s + kk);
      q += v.x * v.x + v.y * v.y + v.z * v.z + v.w * v.w;
    }
    denp = q * ws[WS_DFLAT + (b << 8) + tid];
  }
  float numT = blockRedSum16(num, red);
  float denT = blockRedSum16(denp, red);
  float froT = sqrtf(blockRedSum16(fro2, red));
  float inv_fro = 1.f / froT;
  float osum = 0.f;
  #pragma unroll
  for (int q = 0; q < 4; ++q) {
    float v = accS[q] * inv_fro - ((j0 + q) == k ? 0.125f : 0.f);  // tgt=I/8
    osum += v * v;
  }
  float orT = blockRedSum16(osum, red);
  float* adj = ws + WS_ADJ1 + (size_t)b * 4096;
  float dk = dd[k];
  #pragma unroll
  for (int q = 0; q < 4; ++q) {
    int j = j0 + q;
    adj[k * 64 + j] = (k == j) ? 0.f : accA[q] / (dk * dd[j]);
  }
  if (tid == 0) {
    ws[WS_SCAL + b] = numT / denT;
    ws[WS_SCAL + 16 + b] = sqrtf(orT);
  }
}

// ---------------- K7: x2 = relu(adj1@x1@Wr + br + x1@Ws) (128 blocks)
__global__ __launch_bounds__(256) void k_conv2(float* __restrict__ ws,
                                               const float* __restrict__ Wr,
                                               const float* __restrict__ br,
                                               const float* __restrict__ Ws) {
  int bt = blockIdx.x;
  int b = bt >> 3;
  int tid = threadIdx.x;
  __shared__ float sA[64 * 65];
  __shared__ float sX[64 * 65];
  __shared__ float sY[64 * 65];
  __shared__ float sWr[64 * 65];
  __shared__ float sWs[64 * 65];
  for (int idx = tid; idx < 4096; idx += 256) {
    int r = idx >> 6, c = idx & 63;
    sA[r * 65 + c] = ws[WS_ADJ1 + (size_t)b * 4096 + idx];
    sX[r * 65 + c] = ws[WS_X1 + (size_t)bt * 4096 + idx];
    sWr[r * 65 + c] = Wr[idx];
    sWs[r * 65 + c] = Ws[idx];
  }
  __syncthreads();
  int n = tid >> 2, h0 = (tid & 3) * 16;
  float acc[16];
  #pragma unroll
  for (int q = 0; q < 16; ++q) acc[q] = 0.f;
  for (int m = 0; m < 64; ++m) {
    float a = sA[n * 65 + m];
    #pragma unroll
    for (int q = 0; q < 16; ++q) acc[q] += a * sX[m * 65 + h0 + q];
  }
  #pragma unroll
  for (int q = 0; q < 16; ++q) sY[n * 65 + h0 + q] = acc[q];
  __syncthreads();
  #pragma unroll
  for (int q = 0; q < 16; ++q) acc[q] = br[h0 + q];
  for (int m = 0; m < 64; ++m) {
    float y = sY[n * 65 + m], x = sX[n * 65 + m];
    #pragma unroll
    for (int q = 0; q < 16; ++q)
      acc[q] += y * sWr[m * 65 + h0 + q] + x * sWs[m * 65 + h0 + q];
  }
  #pragma unroll
  for (int q = 0; q < 16; ++q)
    ws[WS_X2 + (size_t)bt * 4096 + n * 64 + h0 + q] = fmaxf(acc[q], 0.f);
}

// ---------------- K8: S2 = softmax(tanh(mean_t(x2)@p2W+p2b)) (1024 blocks x 64)
__global__ __launch_bounds__(64) void k_s2(float* __restrict__ ws,
                                           const float* __restrict__ p2W,
                                           const float* __restrict__ p2b) {
  int bn = blockIdx.x;
  int b = bn >> 6, n = bn & 63;
  int f = threadIdx.x;
  __shared__ float xm[64];
  float s = 0.f;
  #pragma unroll
  for (int t = 0; t < 8; ++t) s += ws[WS_X2 + ((size_t)(b * 8 + t) * 64 + n) * 64 + f];
  xm[f] = s * 0.125f;
  __syncthreads();
  if (f < 32) {
    float acc = p2b[f];
    #pragma unroll 4
    for (int k = 0; k < 64; ++k) acc += xm[k] * p2W[k * 32 + f];
    float v = tanhf(acc);
    float m = v;
    #pragma unroll
    for (int off = 16; off; off >>= 1) m = fmaxf(m, __shfl_xor(m, off, 32));
    float e = __expf(v - m);
    float sum = e;
    #pragma unroll
    for (int off = 16; off; off >>= 1) sum += __shfl_xor(sum, off, 32);
    ws[WS_S2 + (size_t)(b * 64 + n) * 32 + f] = e / sum;
  }
}

// ---------------- K9: x3 = S2^T x2 (blocks 0..127) + pool2 (blocks 128..143)
__global__ __launch_bounds__(256) void k_x3_pool2(float* __restrict__ ws) {
  __shared__ float sm[10700];
  int tid = threadIdx.x, blk = blockIdx.x;
  if (blk < 128) {
    int bt = blk, b = bt >> 3;
    float* sX = sm;           // 64*65
    float* sS = sm + 4160;    // 64*33
    for (int idx = tid; idx < 4096; idx += 256)
      sX[(idx >> 6) * 65 + (idx & 63)] = ws[WS_X2 + (size_t)bt * 4096 + idx];
    for (int idx = tid; idx < 2048; idx += 256)
      sS[(idx >> 5) * 33 + (idx & 31)] = ws[WS_S2 + (size_t)b * 2048 + idx];
    __syncthreads();
    int k = tid >> 3, h0 = (tid & 7) * 8;
    float acc[8];
    #pragma unroll
    for (int q = 0; q < 8; ++q) acc[q] = 0.f;
    for (int n = 0; n < 64; ++n) {
      float sv = sS[n * 33 + k];
      #pragma unroll
      for (int q = 0; q < 8; ++q) acc[q] += sv * sX[n * 65 + h0 + q];
    }
    #pragma unroll
    for (int q = 0; q < 8; ++q)
      ws[WS_X3 + (size_t)bt * 2048 + k * 64 + h0 + q] = acc[q];
  } else {
    int b = blk - 128;
    float* sA = sm;            // 64*65 = 4160
    float* sS2 = sm + 4160;    // 64*33 = 2112
    float* sT = sm + 6272;     // 64*33 = 2112
    float* oaL = sm + 8384;    // 32*33 = 1056
    float* ssL = sm + 9440;    // 32*33 = 1056
    float* sdf = sm + 10496;   // 64
    float* ddL = sm + 10560;   // 32
    float* red = sm + 10592;   // 4
    for (int idx = tid; idx < 4096; idx += 256)
      sA[(idx >> 6) * 65 + (idx & 63)] = ws[WS_ADJ1 + (size_t)b * 4096 + idx];
    for (int idx = tid; idx < 2048; idx += 256)
      sS2[(idx >> 5) * 33 + (idx & 31)] = ws[WS_S2 + (size_t)b * 2048 + idx];
    __syncthreads();
    if (tid < 64) {
      float s = 0.f;
      for (int m = 0; m < 64; ++m) s += sA[tid * 65 + m];
      sdf[tid] = s;
    }
    {
      int n = tid >> 2, j0 = (tid & 3) * 8;
      float acc[8];
      #pragma unroll
      for (int q = 0; q < 8; ++q) acc[q] = 0.f;
      for (int m = 0; m < 64; ++m) {
        float a = sA[n * 65 + m];
        #pragma unroll
        for (int q = 0; q < 8; ++q) acc[q] += a * sS2[m * 33 + j0 + q];
      }
      #pragma unroll
      for (int q = 0; q < 8; ++q) sT[n * 33 + j0 + q] = acc[q];
    }
    float accD = 0.f;
    if (tid < 64) {
      float t = 0.f;
      for (int q = 0; q < 32; ++q) { float v = sS2[tid * 33 + q]; t += v * v; }
      accD = t;
    }
    __syncthreads();
    if (tid < 64) accD *= sdf[tid];
    int k = tid >> 3, j0 = (tid & 7) * 4;
    float accA[4], accS[4];
    #pragma unroll
    for (int q = 0; q < 4; ++q) { accA[q] = 0.f; accS[q] = 0.f; }
    for (int n = 0; n < 64; ++n) {
      float sk = sS2[n * 33 + k];
      #pragma unroll
      for (int q = 0; q < 4; ++q) {
        accA[q] += sk * sT[n * 33 + j0 + q];
        accS[q] += sk * sS2[n * 33 + j0 + q];
      }
    }
    #pragma unroll
    for (int q = 0; q < 4; ++q) {
      oaL[k * 33 + j0 + q] = accA[q];
      ssL[k * 33 + j0 + q] = accS[q];
    }
    float fro2p = 0.f;
    #pragma unroll
    for (int q = 0; q < 4; ++q) fro2p += accS[q] * accS[q];
    __syncthreads();
    float num = 0.f, trs = 0.f;
    if (tid < 32) {
      num = oaL[tid * 33 + tid];
      trs = ssL[tid * 33 + tid];
      float rs = 0.f;
      for (int j = 0; j < 32; ++j) rs += oaL[tid * 33 + j];
      ddL[tid] = sqrtf(fmaxf(rs - num, 0.f)) + 1e-15f;
    }
    float numT = blockRedSum4(num, red);
    float denT = blockRedSum4(accD, red);
    float froT = sqrtf(blockRedSum4(fro2p, red));
    float trT = blockRedSum4(trs, red);
    __syncthreads();
    {
      int idx = tid * 4, kk = idx >> 5, jj = idx & 31;
      float dk = ddL[kk];
      float* a2 = ws + WS_ADJ2 + (size_t)b * 1024;
      #pragma unroll
      for (int q = 0; q < 4; ++q) {
        int j = jj + q;
        a2[kk * 32 + j] = (kk == j) ? 0.f : oaL[kk * 33 + j] / (dk * ddL[j]);
      }
    }
    if (tid == 0) {
      ws[WS_SCAL + 32 + b] = numT / denT;
      ws[WS_SCAL + 48 + b] = sqrtf(fmaxf(2.f - 2.f * trT / (5.656854249f * froT), 0.f));
    }
  }
}

// ---------------- K10: conv3 (0..127) + agg (128..639) + losses (640)
__global__ __launch_bounds__(256) void k_final(float* __restrict__ ws,
                                               const float* __restrict__ Wr,
                                               const float* __restrict__ br,
                                               const float* __restrict__ Ws,
                                               float* __restrict__ out) {
  __shared__ float sm[13600];
  int tid = threadIdx.x, blk = blockIdx.x;
  if (blk < 128) {
    int bt = blk, b = bt >> 3;
    float* sX = sm;            // 32*65 = 2080
    float* sA = sm + 2080;     // 32*33 = 1056
    float* sY = sm + 3136;     // 32*65 = 2080
    float* sWr = sm + 5216;    // 64*65 = 4160
    float* sWs = sm + 9376;    // 64*65 = 4160
    for (int idx = tid; idx < 2048; idx += 256)
      sX[(idx >> 6) * 65 + (idx & 63)] = ws[WS_X3 + (size_t)bt * 2048 + idx];
    for (int idx = tid; idx < 1024; idx += 256)
      sA[(idx >> 5) * 33 + (idx & 31)] = ws[WS_ADJ2 + (size_t)b * 1024 + idx];
    for (int idx = tid; idx < 4096; idx += 256) {
      int r = idx >> 6, c = idx & 63;
      sWr[r * 65 + c] = Wr[idx];
      sWs[r * 65 + c] = Ws[idx];
    }
    __syncthreads();
    int n = tid >> 3, h0 = (tid & 7) * 8;
    float acc[8];
    #pragma unroll
    for (int q = 0; q < 8; ++q) acc[q] = 0.f;
    for (int m = 0; m < 32; ++m) {
      float a = sA[n * 33 + m];
      #pragma unroll
      for (int q = 0; q < 8; ++q) acc[q] += a * sX[m * 65 + h0 + q];
    }
    #pragma unroll
    for (int q = 0; q < 8; ++q) sY[n * 65 + h0 + q] = acc[q];
    __syncthreads();
    #pragma unroll
    for (int q = 0; q < 8; ++q) acc[q] = br[h0 + q];
    for (int m = 0; m < 64; ++m) {
      float y = sY[n * 65 + m], x = sX[n * 65 + m];
      #pragma unroll
      for (int q = 0; q < 8; ++q)
        acc[q] += y * sWr[m * 65 + h0 + q] + x * sWs[m * 65 + h0 + q];
    }
    #pragma unroll
    for (int q = 0; q < 8; ++q) out[(size_t)bt * 2048 + n * 64 + h0 + q] = acc[q];
  } else if (blk < 640) {
    int bi = blk - 128;
    int b = bi >> 5;
    int n0 = (bi & 31) * 8;
    float* sS = sm;  // 64*33
    for (int idx = tid; idx < 2048; idx += 256)
      sS[(idx >> 5) * 33 + (idx & 31)] = ws[WS_S2 + (size_t)b * 2048 + idx];
    __syncthreads();
    int n = n0 + (tid >> 5), j = tid & 31;
    const float* s1r = ws + WS_S1 + ((size_t)((b << 8) + n)) * 64;
    float acc = 0.f;
    #pragma unroll 4
    for (int k = 0; k < 64; ++k) acc += s1r[k] * sS[k * 33 + j];
    out[262146 + ((size_t)((b << 8) + n)) * 32 + j] = acc;
  } else if (tid == 0) {
    float mc = 0.f, o = 0.f;
    #pragma unroll
    for (int b2 = 0; b2 < 16; ++b2) {
      mc += ws[WS_SCAL + b2] + ws[WS_SCAL + 32 + b2];
      o += ws[WS_SCAL + 16 + b2] + ws[WS_SCAL + 48 + b2];
    }
    out[262144] = -mc / 16.0f;
    out[262145] = o / 16.0f;
  }
}

// ================================================================ launch
extern "C" void kernel_launch(void* const* d_in, const int* in_sizes, int n_in,
                              void* d_out, int out_size, void* d_ws, size_t ws_size,
                              hipStream_t stream) {
  (void)in_sizes; (void)n_in; (void)out_size; (void)ws_size;
  const float* pos = (const float*)d_in[0];
  const int* ei = (const int*)d_in[1];
  const float* ea = (const float*)d_in[2];
  const float* W1 = (const float*)d_in[4];
  const float* b1 = (const float*)d_in[5];
  const float* p1W = (const float*)d_in[6];
  const float* p1b = (const float*)d_in[7];
  const float* c2rW = (const float*)d_in[8];
  const float* c2rb = (const float*)d_in[9];
  const float* c2sW = (const float*)d_in[10];
  const float* p2W = (const float*)d_in[11];
  const float* p2b = (const float*)d_in[12];
  const float* c3rW = (const float*)d_in[13];
  const float* c3rb = (const float*)d_in[14];
  const float* c3sW = (const float*)d_in[15];
  float* ws = (float*)d_ws;
  float* out = (float*)d_out;

  hipMemsetAsync(d_ws, 0, (size_t)2097152 * sizeof(float), stream);
  k_p0<<<dim3(8448), dim3(256), 0, stream>>>(pos, W1, ei, ea, ws);
  k_dinv<<<dim3(1024), dim3(256), 0, stream>>>(ws);
  k_gcn_s1<<<dim3(4096), dim3(256), 0, stream>>>(ws, b1, p1W, p1b);
  k_as1_x1<<<dim3(1152), dim3(256), 0, stream>>>(ws);
  k_pool1<<<dim3(16), dim3(1024), 0, stream>>>(ws);
  k_conv2<<<dim3(128), dim3(256), 0, stream>>>(ws, c2rW, c2rb, c2sW);
  k_s2<<<dim3(1024), dim3(64), 0, stream>>>(ws, p2W, p2b);
  k_x3_pool2<<<dim3(144), dim3(256), 0, stream>>>(ws);
  k_final<<<dim3(641), dim3(256), 0, stream>>>(ws, c3rW, c3rb, c3sW, out);
}